// Round 6
// baseline (724.818 us; speedup 1.0000x reference)
//
#include <hip/hip_runtime.h>
#include <hip/hip_bf16.h>

typedef __attribute__((ext_vector_type(8))) short bf16x8;
typedef __attribute__((ext_vector_type(4))) float f32x4;

#define B_ROWS 1024
#define C_COLS 100000
#define K_DIM  512
#define SCALE_S 30.0f
#define MARGIN_M 0.5f
#define EPS_C 1e-7f

// GEMM tile
#define BM 256
#define BN 256
#define BK 64
#define NKT (K_DIM / BK)   // 8 K-tiles
#define N_TILES ((C_COLS + BN - 1) / BN)   // 391

__device__ __forceinline__ void gload_lds16(const __hip_bfloat16* g, __hip_bfloat16* l) {
    __builtin_amdgcn_global_load_lds((const __attribute__((address_space(1))) void*)g,
                                     (__attribute__((address_space(3))) void*)l,
                                     16, 0, 0);
}

__device__ __forceinline__ void barrier_fenced() {
    asm volatile("" ::: "memory");
    __builtin_amdgcn_s_barrier();
    asm volatile("" ::: "memory");
}

// ---------------- L2 normalize rows (fp32 -> bf16), one wave per row ----------------
__global__ __launch_bounds__(256) void l2norm_bf16_rows(const float* __restrict__ in,
                                                        __hip_bfloat16* __restrict__ out,
                                                        int nrows) {
    int wid  = (int)((blockIdx.x * blockDim.x + threadIdx.x) >> 6);
    int lane = threadIdx.x & 63;
    if (wid >= nrows) return;
    const float4* rp = (const float4*)(in + (size_t)wid * K_DIM);
    float4 v0 = rp[lane];
    float4 v1 = rp[lane + 64];
    float ss = v0.x * v0.x + v0.y * v0.y + v0.z * v0.z + v0.w * v0.w
             + v1.x * v1.x + v1.y * v1.y + v1.z * v1.z + v1.w * v1.w;
#pragma unroll
    for (int off = 32; off > 0; off >>= 1) ss += __shfl_xor(ss, off, 64);
    float scale = 1.0f / fmaxf(sqrtf(ss), 1e-12f);
    union { __hip_bfloat16 h[4]; int2 q; } a, b;
    a.h[0] = __float2bfloat16(v0.x * scale);
    a.h[1] = __float2bfloat16(v0.y * scale);
    a.h[2] = __float2bfloat16(v0.z * scale);
    a.h[3] = __float2bfloat16(v0.w * scale);
    b.h[0] = __float2bfloat16(v1.x * scale);
    b.h[1] = __float2bfloat16(v1.y * scale);
    b.h[2] = __float2bfloat16(v1.z * scale);
    b.h[3] = __float2bfloat16(v1.w * scale);
    int2* op = (int2*)(out + (size_t)wid * K_DIM);
    op[lane]      = a.q;
    op[lane + 64] = b.q;
}

// ------ persistent 256x256 4-phase bf16 MFMA GEMM: out[b,c] = 30*dot(A[b],W[c]) ------
// Grid = 256 blocks (1/CU). Block (xcd = bid&7, slot = bid>>3) processes tiles
// j = slot, slot+32, ... of its XCD's list: nt = xcd + 8*(j>>2), mt = j&3 — so the
// 4 M-tiles sharing a W panel run on 4 co-resident blocks of the SAME XCD (L2 reuse),
// and each nt's panel streams from HBM once.
// Tile switch: epilogue stores issue FIRST, then next tile's 8 gloads into buf0,
// then loop-top vmcnt(4) — stores (oldest) + kh0 retire, kh1 stays in flight.
// K-loop schedule/ledger identical to the verified R5 kernel.
__global__ __launch_bounds__(512, 2) void arcface_gemm(
        const __hip_bfloat16* __restrict__ A,   // [1024][512] normalized bf16
        const __hip_bfloat16* __restrict__ W,   // [100000][512] normalized bf16
        float* __restrict__ out) {
    __shared__ __hip_bfloat16 sA[2 * 2 * 256 * 32];   // 64 KiB
    __shared__ __hip_bfloat16 sB[2 * 2 * 256 * 32];   // 64 KiB

    const int x = (int)blockIdx.x & 7;     // intended XCD
    const int s = (int)blockIdx.x >> 3;    // slot 0..31
    const int cnt = (x < (N_TILES & 7)) ? (N_TILES / 8 + 1) : (N_TILES / 8); // nts on this xcd
    const int tot = 4 * cnt;               // tiles on this xcd (192 or 196)

    const int tid  = (int)threadIdx.x;
    const int lane = tid & 63;
    const int w    = tid >> 6;       // 8 waves
    const int wm   = w >> 2;         // 0..1 -> 128-row half
    const int wn   = w & 3;          // 0..3 -> 64-col quarter
    const int lidx = lane & 15, lk = lane >> 4;

    // staging geometry: instr covers rows (tid>>2) + 128*i, physical slot tid&3
    const int srow  = tid >> 2;                  // 0..127
    const int sslot = (tid & 3) ^ (srow & 3);    // pre-swizzled logical slot

#define TILE_MN(j) do { m0 = (long)((j) & 3) * BM;                                  \
                        n0 = (long)(x + 8 * ((j) >> 2)) * BN; } while (0)

#define STAGE_A(buf, kh, kt) do {                                                   \
        gload_lds16(A + (m0 + srow) * K_DIM + (kt) * BK + (kh) * 32 + sslot * 8,    \
                    &sA[((((buf) * 2 + (kh)) * 256) * 32) + (0 * 512 + tid) * 8]);  \
        gload_lds16(A + (m0 + 128 + srow) * K_DIM + (kt) * BK + (kh) * 32 + sslot * 8, \
                    &sA[((((buf) * 2 + (kh)) * 256) * 32) + (1 * 512 + tid) * 8]);  \
    } while (0)

#define STAGE_B(buf, kh, kt) do {                                                   \
        long r0 = n0 + srow;       if (r0 >= C_COLS) r0 = C_COLS - 1;               \
        long r1 = n0 + 128 + srow; if (r1 >= C_COLS) r1 = C_COLS - 1;               \
        gload_lds16(W + r0 * K_DIM + (kt) * BK + (kh) * 32 + sslot * 8,             \
                    &sB[((((buf) * 2 + (kh)) * 256) * 32) + (0 * 512 + tid) * 8]);  \
        gload_lds16(W + r1 * K_DIM + (kt) * BK + (kh) * 32 + sslot * 8,             \
                    &sB[((((buf) * 2 + (kh)) * 256) * 32) + (1 * 512 + tid) * 8]);  \
    } while (0)

#define STAGE_FULL() do { STAGE_A(0, 0, 0); STAGE_B(0, 0, 0);                       \
                          STAGE_A(0, 1, 0); STAGE_B(0, 1, 0); } while (0)

#define LDA(dst, c, kh, mh) do {                                                    \
        _Pragma("unroll")                                                           \
        for (int i = 0; i < 4; ++i) {                                               \
            int row = wm * 128 + (mh) * 64 + i * 16 + lidx;                         \
            dst[i] = *(const bf16x8*)&sA[(((c) * 2 + (kh)) * 256 + row) * 32        \
                                         + ((lk ^ (lidx & 3)) * 8)];                \
        }                                                                           \
    } while (0)

#define LDB(dst, c, kh) do {                                                        \
        _Pragma("unroll")                                                           \
        for (int n = 0; n < 4; ++n) {                                               \
            int row = wn * 64 + n * 16 + lidx;                                      \
            dst[n] = *(const bf16x8*)&sB[(((c) * 2 + (kh)) * 256 + row) * 32        \
                                         + ((lk ^ (lidx & 3)) * 8)];                \
        }                                                                           \
    } while (0)

// Swapped operands: D = W_frag x A_frag -> lane holds out[b = ..+lidx][c = ..+lk*4+j],
// j contiguous in memory -> float4 stores. Same dot products, new fragment meaning.
#define MFMA16(mh, av_, bv_) do {                                                   \
        __builtin_amdgcn_s_setprio(1);                                              \
        _Pragma("unroll")                                                           \
        for (int m = 0; m < 4; ++m)                                                 \
            _Pragma("unroll")                                                       \
            for (int n = 0; n < 4; ++n)                                             \
                acc[(mh) * 4 + m][n] = __builtin_amdgcn_mfma_f32_16x16x32_bf16(     \
                    bv_[n], av_[m], acc[(mh) * 4 + m][n], 0, 0, 0);                 \
        __builtin_amdgcn_s_setprio(0);                                              \
    } while (0)

#define WAIT_LGKM0() do { asm volatile("s_waitcnt lgkmcnt(0)" ::: "memory"); \
                          __builtin_amdgcn_sched_barrier(0); } while (0)
#define WAIT_VM4()   asm volatile("s_waitcnt vmcnt(4)" ::: "memory")
#define WAIT_VM0()   asm volatile("s_waitcnt vmcnt(0)" ::: "memory")

    f32x4 acc[8][4];
    bf16x8 av[4], bv[4];
    long m0, n0;

    // prologue: stage first tile's K-tile 0 into buf0 (kh0 first, then kh1)
    TILE_MN(s);
    STAGE_FULL();

    for (int j = s; j < tot; j += 32) {
        WAIT_VM4();             // retire stores (oldest) + S(0,kh0); kh1 in flight
        barrier_fenced();
#pragma unroll
        for (int m = 0; m < 8; ++m)
#pragma unroll
            for (int n = 0; n < 4; ++n) acc[m][n] = (f32x4){0.f, 0.f, 0.f, 0.f};

        for (int t = 0; t < NKT - 1; ++t) {
            const int c = t & 1, nb = c ^ 1;
            // P1 (mh0, kh0)
            LDA(av, c, 0, 0); LDB(bv, c, 0);
            STAGE_A(nb, 0, t + 1);
            barrier_fenced(); WAIT_LGKM0();
            MFMA16(0, av, bv);
            barrier_fenced();
            // P2 (mh1, kh0) — reuse bv
            LDA(av, c, 0, 1);
            STAGE_B(nb, 0, t + 1);
            barrier_fenced(); WAIT_LGKM0();
            MFMA16(1, av, bv);
            WAIT_VM4();         // retire S(t,kh1) before P3 reads it
            barrier_fenced();
            // P3 (mh0, kh1)
            LDA(av, c, 1, 0); LDB(bv, c, 1);
            STAGE_A(nb, 1, t + 1);
            barrier_fenced(); WAIT_LGKM0();
            MFMA16(0, av, bv);
            barrier_fenced();
            // P4 (mh1, kh1)
            LDA(av, c, 1, 1);
            STAGE_B(nb, 1, t + 1);
            barrier_fenced(); WAIT_LGKM0();
            MFMA16(1, av, bv);
            WAIT_VM4();         // retire S(t+1,kh0) before next-iter P1 reads it
            barrier_fenced();
        }
        {   // peeled last K-tile, no staging
            const int c = (NKT - 1) & 1;   // buf1
            LDA(av, c, 0, 0); LDB(bv, c, 0);
            barrier_fenced(); WAIT_LGKM0();
            MFMA16(0, av, bv);
            barrier_fenced();
            LDA(av, c, 0, 1);
            barrier_fenced(); WAIT_LGKM0();
            MFMA16(1, av, bv);
            WAIT_VM0();         // drain S(last,kh1)
            barrier_fenced();
            LDA(av, c, 1, 0); LDB(bv, c, 1);
            barrier_fenced(); WAIT_LGKM0();
            MFMA16(0, av, bv);
            barrier_fenced();
            LDA(av, c, 1, 1);
            barrier_fenced(); WAIT_LGKM0();
            MFMA16(1, av, bv);
        }

        // epilogue: lane (lidx,lk) holds out[b][c0..c0+3] per fragment -> float4 stores.
        // b = m0 + wm*128 + mf*16 + lidx ; c0 = n0 + wn*64 + nf*16 + lk*4.
        // C_COLS % 4 == 0 -> each float4 is fully in- or out-of-bounds.
        {
            const long cb = n0 + wn * 64 + lk * 4;
#pragma unroll
            for (int mf = 0; mf < 8; ++mf) {
                float* orow = out + (m0 + wm * 128 + mf * 16 + lidx) * (long)C_COLS;
#pragma unroll
                for (int nf = 0; nf < 4; ++nf) {
                    long c0 = cb + nf * 16;
                    if (c0 < C_COLS) {
                        float4 st = { acc[mf][nf][0] * SCALE_S, acc[mf][nf][1] * SCALE_S,
                                      acc[mf][nf][2] * SCALE_S, acc[mf][nf][3] * SCALE_S };
                        *(float4*)(orow + c0) = st;
                    }
                }
            }
        }

        // prefetch next tile's K-tile 0 into buf0 (safe: buf0 last read at t=NKT-2,
        // fenced by that iteration's trailing barrier; peel reads buf1 only).
        if (j + 32 < tot) {
            TILE_MN(j + 32);
            STAGE_FULL();
        }
    }
#undef TILE_MN
#undef STAGE_A
#undef STAGE_B
#undef STAGE_FULL
#undef LDA
#undef LDB
#undef MFMA16
#undef WAIT_LGKM0
#undef WAIT_VM4
#undef WAIT_VM0
}

// ---------------- per-row margin fixup at the label column ----------------
__global__ void margin_fixup(float* __restrict__ out, const int* __restrict__ labels,
                             int nrows) {
    int b = blockIdx.x * blockDim.x + threadIdx.x;
    if (b >= nrows) return;
    int lab = labels[b];
    size_t idx = (size_t)b * C_COLS + (size_t)lab;
    float c = out[idx] * (1.0f / SCALE_S);
    c = fminf(fmaxf(c, -1.0f + EPS_C), 1.0f - EPS_C);
    float t = acosf(c) + MARGIN_M;
    out[idx] = cosf(t) * SCALE_S;
}

extern "C" void kernel_launch(void* const* d_in, const int* in_sizes, int n_in,
                              void* d_out, int out_size, void* d_ws, size_t ws_size,
                              hipStream_t stream) {
    const float* emb = (const float*)d_in[0];   // [1024,512]
    const float* wgt = (const float*)d_in[1];   // [100000,512]
    const int* labels = (const int*)d_in[2];    // [1024]
    float* out = (float*)d_out;                 // [1024,100000]

    __hip_bfloat16* embb = (__hip_bfloat16*)d_ws;
    __hip_bfloat16* wgtb = (__hip_bfloat16*)((char*)d_ws + (size_t)B_ROWS * K_DIM * 2);

    l2norm_bf16_rows<<<B_ROWS / 4, 256, 0, stream>>>(emb, embb, B_ROWS);
    l2norm_bf16_rows<<<C_COLS / 4, 256, 0, stream>>>(wgt, wgtb, C_COLS);

    arcface_gemm<<<256, 512, 0, stream>>>(embb, wgtb, out);   // persistent, 1 block/CU

    margin_fixup<<<(B_ROWS + 255) / 256, 256, 0, stream>>>(out, labels, B_ROWS);
}

// Round 9
// 703.133 us; speedup vs baseline: 1.0308x; 1.0308x over previous
//
#include <hip/hip_runtime.h>
#include <hip/hip_bf16.h>

typedef __attribute__((ext_vector_type(8))) short bf16x8;
typedef __attribute__((ext_vector_type(4))) float f32x4;

#define B_ROWS 1024
#define C_COLS 100000
#define K_DIM  512
#define SCALE_S 30.0f
#define MARGIN_M 0.5f
#define EPS_C 1e-7f

// GEMM tile
#define BM 256
#define BN 256
#define BK 64
#define NKT (K_DIM / BK)   // 8 K-tiles

__device__ __forceinline__ void gload_lds16(const __hip_bfloat16* g, __hip_bfloat16* l) {
    __builtin_amdgcn_global_load_lds((const __attribute__((address_space(1))) void*)g,
                                     (__attribute__((address_space(3))) void*)l,
                                     16, 0, 0);
}

__device__ __forceinline__ void barrier_fenced() {
    asm volatile("" ::: "memory");
    __builtin_amdgcn_s_barrier();
    asm volatile("" ::: "memory");
}

// ---------------- L2 normalize rows (fp32 -> bf16), one wave per row ----------------
__global__ __launch_bounds__(256) void l2norm_bf16_rows(const float* __restrict__ in,
                                                        __hip_bfloat16* __restrict__ out,
                                                        int nrows) {
    int wid  = (int)((blockIdx.x * blockDim.x + threadIdx.x) >> 6);
    int lane = threadIdx.x & 63;
    if (wid >= nrows) return;
    const float4* rp = (const float4*)(in + (size_t)wid * K_DIM);
    float4 v0 = rp[lane];          // fully contiguous per instruction
    float4 v1 = rp[lane + 64];
    float ss = v0.x * v0.x + v0.y * v0.y + v0.z * v0.z + v0.w * v0.w
             + v1.x * v1.x + v1.y * v1.y + v1.z * v1.z + v1.w * v1.w;
#pragma unroll
    for (int off = 32; off > 0; off >>= 1) ss += __shfl_xor(ss, off, 64);
    float scale = 1.0f / fmaxf(sqrtf(ss), 1e-12f);
    union { __hip_bfloat16 h[4]; int2 q; } a, b;
    a.h[0] = __float2bfloat16(v0.x * scale);
    a.h[1] = __float2bfloat16(v0.y * scale);
    a.h[2] = __float2bfloat16(v0.z * scale);
    a.h[3] = __float2bfloat16(v0.w * scale);
    b.h[0] = __float2bfloat16(v1.x * scale);
    b.h[1] = __float2bfloat16(v1.y * scale);
    b.h[2] = __float2bfloat16(v1.z * scale);
    b.h[3] = __float2bfloat16(v1.w * scale);
    int2* op = (int2*)(out + (size_t)wid * K_DIM);
    op[lane]      = a.q;
    op[lane + 64] = b.q;
}

// ---------------- 256x256 8-phase bf16 MFMA GEMM: out[b,c] = 30*dot(A[b],W[c]) ----------------
// LDS per matrix: [2 buf][2 khalf][256 rows][32 cols] bf16 (rows 64B). 128 KiB total.
// Stage unit S(kt,kh) = A[256][32]+B[256][32] (contiguous), 8 gloads per K-tile.
// Swizzle: physical 16B slot p at row r holds logical slot p ^ (r&3)
// (pre-swizzled global source on write, XORed slot on ds_read — rule #21 involution).
__global__ __launch_bounds__(512, 2) void arcface_gemm(
        const __hip_bfloat16* __restrict__ A,   // [1024][512] normalized bf16
        const __hip_bfloat16* __restrict__ W,   // [100000][512] normalized bf16
        float* __restrict__ out) {
    __shared__ __hip_bfloat16 sA[2 * 2 * 256 * 32];   // 64 KiB
    __shared__ __hip_bfloat16 sB[2 * 2 * 256 * 32];   // 64 KiB

    // bijective XCD swizzle (m204), nwg = 1564 (not divisible by 8)
    const int nwg = (int)gridDim.x;
    const int q8 = nwg >> 3, r8 = nwg & 7;
    const int xcd = (int)blockIdx.x & 7, ii = (int)blockIdx.x >> 3;
    const int wg = (xcd < r8 ? xcd * (q8 + 1) : r8 * (q8 + 1) + (xcd - r8) * q8) + ii;
    const int mt = wg & 3, nt = wg >> 2;        // M fastest: 4 M-tiles share W panel in L2
    const long m0 = (long)mt * BM;
    const long n0 = (long)nt * BN;

    const int tid  = (int)threadIdx.x;
    const int lane = tid & 63;
    const int w    = tid >> 6;       // 8 waves
    const int wm   = w >> 2;         // 0..1 -> 128-row half
    const int wn   = w & 3;          // 0..3 -> 64-col quarter
    const int lidx = lane & 15, lk = lane >> 4;

    // staging geometry: instr j covers rows j*128 + (tid>>2), physical slot tid&3
    const int srow  = tid >> 2;                  // 0..127
    const int sslot = (tid & 3) ^ (srow & 3);    // pre-swizzled logical slot

#define STAGE_A(buf, kh, kt) do {                                                   \
        gload_lds16(A + (m0 + srow) * K_DIM + (kt) * BK + (kh) * 32 + sslot * 8,    \
                    &sA[((((buf) * 2 + (kh)) * 256) * 32) + (0 * 512 + tid) * 8]);  \
        gload_lds16(A + (m0 + 128 + srow) * K_DIM + (kt) * BK + (kh) * 32 + sslot * 8, \
                    &sA[((((buf) * 2 + (kh)) * 256) * 32) + (1 * 512 + tid) * 8]);  \
    } while (0)

#define STAGE_B(buf, kh, kt) do {                                                   \
        long r0 = n0 + srow;       if (r0 >= C_COLS) r0 = C_COLS - 1;               \
        long r1 = n0 + 128 + srow; if (r1 >= C_COLS) r1 = C_COLS - 1;               \
        gload_lds16(W + r0 * K_DIM + (kt) * BK + (kh) * 32 + sslot * 8,             \
                    &sB[((((buf) * 2 + (kh)) * 256) * 32) + (0 * 512 + tid) * 8]);  \
        gload_lds16(W + r1 * K_DIM + (kt) * BK + (kh) * 32 + sslot * 8,             \
                    &sB[((((buf) * 2 + (kh)) * 256) * 32) + (1 * 512 + tid) * 8]);  \
    } while (0)

#define LDA(dst, c, kh, mh) do {                                                    \
        _Pragma("unroll")                                                           \
        for (int i = 0; i < 4; ++i) {                                               \
            int row = wm * 128 + (mh) * 64 + i * 16 + lidx;                         \
            dst[i] = *(const bf16x8*)&sA[(((c) * 2 + (kh)) * 256 + row) * 32        \
                                         + ((lk ^ (lidx & 3)) * 8)];                \
        }                                                                           \
    } while (0)

#define LDB(dst, c, kh) do {                                                        \
        _Pragma("unroll")                                                           \
        for (int n = 0; n < 4; ++n) {                                               \
            int row = wn * 64 + n * 16 + lidx;                                      \
            dst[n] = *(const bf16x8*)&sB[(((c) * 2 + (kh)) * 256 + row) * 32        \
                                         + ((lk ^ (lidx & 3)) * 8)];                \
        }                                                                           \
    } while (0)

#define MFMA16(mh, av_, bv_) do {                                                   \
        __builtin_amdgcn_s_setprio(1);                                              \
        _Pragma("unroll")                                                           \
        for (int m = 0; m < 4; ++m)                                                 \
            _Pragma("unroll")                                                       \
            for (int n = 0; n < 4; ++n)                                             \
                acc[(mh) * 4 + m][n] = __builtin_amdgcn_mfma_f32_16x16x32_bf16(     \
                    av_[m], bv_[n], acc[(mh) * 4 + m][n], 0, 0, 0);                 \
        __builtin_amdgcn_s_setprio(0);                                              \
    } while (0)

#define WAIT_LGKM0() do { asm volatile("s_waitcnt lgkmcnt(0)" ::: "memory"); \
                          __builtin_amdgcn_sched_barrier(0); } while (0)
#define WAIT_VM4()   asm volatile("s_waitcnt vmcnt(4)" ::: "memory")
#define WAIT_VM0()   asm volatile("s_waitcnt vmcnt(0)" ::: "memory")

    f32x4 acc[8][4];
#pragma unroll
    for (int m = 0; m < 8; ++m)
#pragma unroll
        for (int n = 0; n < 4; ++n) acc[m][n] = (f32x4){0.f, 0.f, 0.f, 0.f};

    // prologue: K-tile 0 -> buf0 (kh0 first, then kh1)
    STAGE_A(0, 0, 0); STAGE_B(0, 0, 0);
    STAGE_A(0, 1, 0); STAGE_B(0, 1, 0);
    WAIT_VM4();                 // retire S(0,kh0); S(0,kh1) stays in flight
    barrier_fenced();

    bf16x8 av[4], bv[4];
    for (int t = 0; t < NKT - 1; ++t) {
        const int c = t & 1, nb = c ^ 1;
        // P1 (mh0, kh0)
        LDA(av, c, 0, 0); LDB(bv, c, 0);
        STAGE_A(nb, 0, t + 1);
        barrier_fenced(); WAIT_LGKM0();
        MFMA16(0, av, bv);
        barrier_fenced();
        // P2 (mh1, kh0) — reuse bv
        LDA(av, c, 0, 1);
        STAGE_B(nb, 0, t + 1);
        barrier_fenced(); WAIT_LGKM0();
        MFMA16(1, av, bv);
        WAIT_VM4();             // retire S(t,kh1) before P3 reads it
        barrier_fenced();
        // P3 (mh0, kh1)
        LDA(av, c, 1, 0); LDB(bv, c, 1);
        STAGE_A(nb, 1, t + 1);
        barrier_fenced(); WAIT_LGKM0();
        MFMA16(0, av, bv);
        barrier_fenced();
        // P4 (mh1, kh1)
        LDA(av, c, 1, 1);
        STAGE_B(nb, 1, t + 1);
        barrier_fenced(); WAIT_LGKM0();
        MFMA16(1, av, bv);
        WAIT_VM4();             // retire S(t+1,kh0) before next-iter P1 reads it
        barrier_fenced();
    }
    {   // peeled last K-tile, no staging
        const int c = (NKT - 1) & 1;
        LDA(av, c, 0, 0); LDB(bv, c, 0);
        barrier_fenced(); WAIT_LGKM0();
        MFMA16(0, av, bv);
        barrier_fenced();
        LDA(av, c, 0, 1);
        barrier_fenced(); WAIT_LGKM0();
        MFMA16(1, av, bv);
        WAIT_VM0();             // retire S(NKT-1,kh1)
        barrier_fenced();
        LDA(av, c, 1, 0); LDB(bv, c, 1);
        barrier_fenced(); WAIT_LGKM0();
        MFMA16(0, av, bv);
        barrier_fenced();
        LDA(av, c, 1, 1);
        barrier_fenced(); WAIT_LGKM0();
        MFMA16(1, av, bv);
    }

    // epilogue: C/D layout col = lidx, row = lk*4 + j (m89-verified), scale by 30
    const long colb = n0 + wn * 64 + lidx;
#pragma unroll
    for (int mf = 0; mf < 8; ++mf) {
        long rowb = m0 + wm * 128 + mf * 16 + lk * 4;
#pragma unroll
        for (int nf = 0; nf < 4; ++nf) {
            long gc = colb + nf * 16;
            if (gc < C_COLS) {
#pragma unroll
                for (int j = 0; j < 4; ++j)
                    out[(rowb + j) * (long)C_COLS + gc] = acc[mf][nf][j] * SCALE_S;
            }
        }
    }
#undef STAGE_A
#undef STAGE_B
#undef LDA
#undef LDB
#undef MFMA16
#undef WAIT_LGKM0
#undef WAIT_VM4
#undef WAIT_VM0
}

// ---------------- per-row margin fixup at the label column ----------------
__global__ void margin_fixup(float* __restrict__ out, const int* __restrict__ labels,
                             int nrows) {
    int b = blockIdx.x * blockDim.x + threadIdx.x;
    if (b >= nrows) return;
    int lab = labels[b];
    size_t idx = (size_t)b * C_COLS + (size_t)lab;
    float c = out[idx] * (1.0f / SCALE_S);
    c = fminf(fmaxf(c, -1.0f + EPS_C), 1.0f - EPS_C);
    float t = acosf(c) + MARGIN_M;
    out[idx] = cosf(t) * SCALE_S;
}

extern "C" void kernel_launch(void* const* d_in, const int* in_sizes, int n_in,
                              void* d_out, int out_size, void* d_ws, size_t ws_size,
                              hipStream_t stream) {
    const float* emb = (const float*)d_in[0];   // [1024,512]
    const float* wgt = (const float*)d_in[1];   // [100000,512]
    const int* labels = (const int*)d_in[2];    // [1024]
    float* out = (float*)d_out;                 // [1024,100000]

    __hip_bfloat16* embb = (__hip_bfloat16*)d_ws;
    __hip_bfloat16* wgtb = (__hip_bfloat16*)((char*)d_ws + (size_t)B_ROWS * K_DIM * 2);

    l2norm_bf16_rows<<<B_ROWS / 4, 256, 0, stream>>>(emb, embb, B_ROWS);
    l2norm_bf16_rows<<<C_COLS / 4, 256, 0, stream>>>(wgt, wgtb, C_COLS);

    const int ntiles = (C_COLS + BN - 1) / BN;  // 391
    arcface_gemm<<<4 * ntiles, 512, 0, stream>>>(embb, wgtb, out);

    margin_fixup<<<(B_ROWS + 255) / 256, 256, 0, stream>>>(out, labels, B_ROWS);
}